// Round 1
// baseline (470.365 us; speedup 1.0000x reference)
//
#include <hip/hip_runtime.h>
#include <stdint.h>

// Problem constants
#define B 8
#define N 2048
#define D 16
#define KNN 32
#define DM 256

// ---------------------------------------------------------------------------
// K1: per-(b, channel) mean/std over N (ddof=1), two-pass for accuracy.
// grid = B*32 blocks (one per (b,c)), 256 threads.
// ---------------------------------------------------------------------------
__global__ __launch_bounds__(256) void knn_stats(
    const float* __restrict__ x, const float* __restrict__ features,
    float* __restrict__ mean_out, float* __restrict__ scale_out)
{
    int b = blockIdx.x >> 5;
    int c = blockIdx.x & 31;
    int d = c & 15;
    bool ftr_side = (c >= 16);
    bool mask = features[b * D + d] > 0.1f;
    bool pass = ftr_side ? mask : !mask;   // value = pass ? x : 0

    __shared__ float red[256];
    float s = 0.f;
    for (int n = threadIdx.x; n < N; n += 256) {
        float xv = pass ? x[((size_t)b * N + n) * D + d] : 0.f;
        s += xv;
    }
    red[threadIdx.x] = s; __syncthreads();
    for (int st = 128; st > 0; st >>= 1) {
        if (threadIdx.x < st) red[threadIdx.x] += red[threadIdx.x + st];
        __syncthreads();
    }
    float mean = red[0] / (float)N;
    __syncthreads();

    float s2 = 0.f;
    for (int n = threadIdx.x; n < N; n += 256) {
        float xv = pass ? x[((size_t)b * N + n) * D + d] : 0.f;
        float dv = xv - mean;
        s2 += dv * dv;
    }
    red[threadIdx.x] = s2; __syncthreads();
    for (int st = 128; st > 0; st >>= 1) {
        if (threadIdx.x < st) red[threadIdx.x] += red[threadIdx.x + st];
        __syncthreads();
    }
    if (threadIdx.x == 0) {
        float var  = red[0] / (float)(N - 1);
        float stdv = sqrtf(var);
        mean_out[b * 32 + c]  = mean;
        scale_out[b * 32 + c] = 1.f / (stdv + 1e-5f);
    }
}

// ---------------------------------------------------------------------------
// K2: per-point raw masked x_crd row, sq = sum(x_crd^2), and normalized
// channel sums Tc (crd half), Tf (ftr half).  16384 threads.
// ---------------------------------------------------------------------------
__global__ __launch_bounds__(256) void knn_prep(
    const float* __restrict__ x, const float* __restrict__ features,
    const float* __restrict__ mean_, const float* __restrict__ scale_,
    float* __restrict__ xcrd, float* __restrict__ sq,
    float* __restrict__ Tc, float* __restrict__ Tf)
{
    int t = blockIdx.x * 256 + threadIdx.x;      // (b,n) flat, 0..16383
    int b = t >> 11;
    float tc = 0.f, tf = 0.f, s = 0.f;
    float row[D];
#pragma unroll
    for (int d = 0; d < D; ++d) {
        float xv = x[(size_t)t * D + d];
        bool mask = features[b * D + d] > 0.1f;
        float xc = mask ? 0.f : xv;
        float xf = mask ? xv : 0.f;
        row[d] = xc;
        s += xc * xc;                            // sequential, mirrors ref sq
        float vc = (xc - mean_[b * 32 + d])      * scale_[b * 32 + d];
        vc = fminf(10.f, fmaxf(-10.f, vc));
        float vf = (xf - mean_[b * 32 + 16 + d]) * scale_[b * 32 + 16 + d];
        vf = fminf(10.f, fmaxf(-10.f, vf));
        tc += vc; tf += vf;
    }
#pragma unroll
    for (int d = 0; d < D; d += 4)
        *(float4*)(xcrd + (size_t)t * D + d) =
            make_float4(row[d], row[d+1], row[d+2], row[d+3]);
    sq[t] = s; Tc[t] = tc; Tf[t] = tf;
}

// ---------------------------------------------------------------------------
// K3: transpose W (DM,K)->(K,DM) for coalesced column reads; bias const
// cbias[dm] = sum_p(pe_crd+pe_ftr); pe_loss scalar.  1 block x 256.
// ---------------------------------------------------------------------------
__global__ __launch_bounds__(256) void knn_wprep(
    const float* __restrict__ Wc, const float* __restrict__ Wf,
    const float* __restrict__ pec, const float* __restrict__ pef,
    float* __restrict__ WcT, float* __restrict__ WfT,
    float* __restrict__ cbias, float* __restrict__ pe_loss_out)
{
    int dm = threadIdx.x;
    float cb = 0.f, al = 0.f;
#pragma unroll
    for (int p = 0; p < D; ++p)
        cb += pec[p * DM + dm] + pef[p * DM + dm];
#pragma unroll
    for (int p = 0; p < D; ++p)
        al += fabsf(pec[p * DM + dm]) + fabsf(pef[p * DM + dm]);
    cbias[dm] = cb;
#pragma unroll
    for (int k = 0; k < KNN; ++k) {
        WcT[k * DM + dm] = Wc[dm * KNN + k];
        WfT[k * DM + dm] = Wf[dm * KNN + k];
    }
    __shared__ float red[256];
    red[dm] = al; __syncthreads();
    for (int st = 128; st > 0; st >>= 1) {
        if (dm < st) red[dm] += red[dm + st];
        __syncthreads();
    }
    if (dm == 0) pe_loss_out[0] = red[0];
}

// ---------------------------------------------------------------------------
// K4: one wave (64 lanes) per query. Each lane holds 32 candidate distance
// keys in registers (m = j*64 + lane). 32 rounds: wave-min butterfly over
// lexicographic key (dist_bits<<11 | m)  [jax tie-break: lower index first],
// winner lane invalidates + rescans its register array (static-index unroll),
// all lanes incrementally accumulate the 32->256 matvec with transposed W.
// ---------------------------------------------------------------------------
__global__ __launch_bounds__(256) void knn_main(
    const float* __restrict__ xcrd, const float* __restrict__ sq,
    const float* __restrict__ Tc, const float* __restrict__ Tf,
    const float* __restrict__ WcT, const float* __restrict__ WfT,
    const float* __restrict__ cbias, float* __restrict__ out)
{
    const int wave = threadIdx.x >> 6;
    const int lane = threadIdx.x & 63;
    const int qid  = blockIdx.x * 4 + wave;      // 0..16383
    const int b = qid >> 11;
    const int n = qid & 2047;

    const float* xb  = xcrd + (size_t)b * N * D;
    const float* sqb = sq + b * N;

    // query row
    float qx[D];
#pragma unroll
    for (int d = 0; d < D; d += 4) {
        float4 v = *(const float4*)(xb + (size_t)n * D + d);
        qx[d] = v.x; qx[d+1] = v.y; qx[d+2] = v.z; qx[d+3] = v.w;
    }
    const float sqn = sqb[n];

    // fill 32 candidate keys per lane
    uint32_t bits[KNN];
#pragma unroll
    for (int j = 0; j < KNN; ++j) {
        int m = j * 64 + lane;
        const float* xm = xb + (size_t)m * D;
        float mr[D];
#pragma unroll
        for (int d = 0; d < D; d += 4) {
            float4 v = *(const float4*)(xm + d);
            mr[d] = v.x; mr[d+1] = v.y; mr[d+2] = v.z; mr[d+3] = v.w;
        }
        float dot = 0.f;
#pragma unroll
        for (int d = 0; d < D; ++d) dot += qx[d] * mr[d];  // sequential: self-dist == 0
        float d2 = sqn + sqb[m] - 2.0f * dot;
        float dist = sqrtf(fmaxf(d2, 0.f));
        bits[j] = __float_as_uint(dist);
    }

    // lane-local min (lexicographic (bits, j); strict < keeps lower j on ties)
    uint32_t alive = 0xffffffffu;
    uint32_t lmin = 0xffffffffu; int lj = 0;
#pragma unroll
    for (int j = 0; j < KNN; ++j)
        if (bits[j] < lmin) { lmin = bits[j]; lj = j; }

    float acc[4] = {0.f, 0.f, 0.f, 0.f};
    const float* Tcb = Tc + b * N;
    const float* Tfb = Tf + b * N;
    const float Tcn = Tcb[n], Tfn = Tfb[n];

#pragma unroll 1
    for (int k = 0; k < KNN; ++k) {
        unsigned long long key =
            ((unsigned long long)lmin << 11) | (unsigned)(lj * 64 + lane);
#pragma unroll
        for (int s = 32; s >= 1; s >>= 1) {
            unsigned long long o = __shfl_xor(key, s, 64);
            key = (o < key) ? o : key;
        }
        int wm = (int)(key & 2047u);             // k-th nearest (global index in batch)

        if ((wm & 63) == lane) {                 // winner lane: invalidate + rescan
            alive &= ~(1u << (wm >> 6));
            uint32_t nm = 0xffffffffu; int nj = 0;
#pragma unroll
            for (int j = 0; j < KNN; ++j)
                if (((alive >> j) & 1u) && bits[j] < nm) { nm = bits[j]; nj = j; }
            lmin = nm; lj = nj;
        }

        float ak = Tcb[wm] - Tcn;
        float bk = Tfb[wm] - Tfn;
        const float* wc = WcT + k * DM + lane;
        const float* wf = WfT + k * DM + lane;
#pragma unroll
        for (int q = 0; q < 4; ++q)
            acc[q] += wc[q * 64] * ak + wf[q * 64] * bk;
    }

    size_t obase = (size_t)qid * DM + lane;
#pragma unroll
    for (int q = 0; q < 4; ++q)
        out[obase + q * 64] = acc[q] + cbias[lane + q * 64];
}

// ---------------------------------------------------------------------------
extern "C" void kernel_launch(void* const* d_in, const int* in_sizes, int n_in,
                              void* d_out, int out_size, void* d_ws, size_t ws_size,
                              hipStream_t stream)
{
    const float* x        = (const float*)d_in[0];   // (B,N,D)
    const float* features = (const float*)d_in[1];   // (B,D)
    const float* W_crd    = (const float*)d_in[2];   // (DM,K)
    const float* W_ftr    = (const float*)d_in[3];   // (DM,K)
    const float* pe_crd   = (const float*)d_in[4];   // (1,1,D,DM)
    const float* pe_ftr   = (const float*)d_in[5];   // (1,1,D,DM)
    // d_in[6] = k (constant 32), ignored

    float* out = (float*)d_out;                      // B*N*DM floats + 1 (pe_loss)

    float* W     = (float*)d_ws;
    float* xcrd  = W;                    // 262144
    float* sqv   = xcrd + (size_t)B * N * D;   // 16384
    float* Tc    = sqv  + B * N;         // 16384
    float* Tf    = Tc   + B * N;         // 16384
    float* mean_ = Tf   + B * N;         // 256
    float* scale = mean_ + B * 32;       // 256
    float* cbias = scale + B * 32;       // 256
    float* WcT   = cbias + DM;           // 8192
    float* WfT   = WcT + KNN * DM;       // 8192

    knn_stats<<<B * 32, 256, 0, stream>>>(x, features, mean_, scale);
    knn_prep <<<B * N / 256, 256, 0, stream>>>(x, features, mean_, scale,
                                               xcrd, sqv, Tc, Tf);
    knn_wprep<<<1, 256, 0, stream>>>(W_crd, W_ftr, pe_crd, pe_ftr,
                                     WcT, WfT, cbias, out + (size_t)out_size - 1);
    knn_main <<<B * N / 4, 256, 0, stream>>>(xcrd, sqv, Tc, Tf,
                                             WcT, WfT, cbias, out);
}

// Round 2
// 303.030 us; speedup vs baseline: 1.5522x; 1.5522x over previous
//
#include <hip/hip_runtime.h>
#include <stdint.h>

// Problem constants
#define B 8
#define N 2048
#define D 16
#define KNN 32
#define DM 256

// ---------------------------------------------------------------------------
// K1: per-(b,channel) mean/scale. One block per batch, single coalesced pass,
// fp64 sum/sumsq accumulation, shuffle reduce. Channel c<16 = crd half,
// c>=16 = ftr half; the masked-out half is all zeros (mean 0, std 0).
// ---------------------------------------------------------------------------
__global__ __launch_bounds__(256) void knn_stats(
    const float* __restrict__ x, const float* __restrict__ features,
    float* __restrict__ mean_out, float* __restrict__ scale_out)
{
    int b = blockIdx.x;
    int tid = threadIdx.x;
    double ls[D], lq[D];
#pragma unroll
    for (int d = 0; d < D; ++d) { ls[d] = 0.0; lq[d] = 0.0; }

    for (int n = tid; n < N; n += 256) {
        const float* row = x + ((size_t)b * N + n) * D;
#pragma unroll
        for (int d = 0; d < D; d += 4) {
            float4 v = *(const float4*)(row + d);
            double x0 = v.x, x1 = v.y, x2 = v.z, x3 = v.w;
            ls[d]   += x0; lq[d]   += x0 * x0;
            ls[d+1] += x1; lq[d+1] += x1 * x1;
            ls[d+2] += x2; lq[d+2] += x2 * x2;
            ls[d+3] += x3; lq[d+3] += x3 * x3;
        }
    }
    // wave butterfly reduce
#pragma unroll
    for (int d = 0; d < D; ++d) {
        double s = ls[d], q = lq[d];
#pragma unroll
        for (int st = 32; st >= 1; st >>= 1) {
            s += __shfl_xor(s, st, 64);
            q += __shfl_xor(q, st, 64);
        }
        ls[d] = s; lq[d] = q;
    }
    __shared__ double sred[4][2 * D];
    int wave = tid >> 6, lane = tid & 63;
    if (lane == 0) {
#pragma unroll
        for (int d = 0; d < D; ++d) {
            sred[wave][d]     = ls[d];
            sred[wave][D + d] = lq[d];
        }
    }
    __syncthreads();
    if (tid < D) {
        int d = tid;
        double S = sred[0][d] + sred[1][d] + sred[2][d] + sred[3][d];
        double Q = sred[0][D+d] + sred[1][D+d] + sred[2][D+d] + sred[3][D+d];
        double mean = S / (double)N;
        double var  = (Q - S * S / (double)N) / (double)(N - 1);
        if (var < 0.0) var = 0.0;
        float stdv  = (float)sqrt(var);
        float scl   = 1.0f / (stdv + 1e-5f);
        float scl0  = 1.0f / (0.0f + 1e-5f);
        bool mask = features[b * D + d] > 0.1f;
        // crd half (c=d): zero column if mask; ftr half (c=16+d): zero if !mask
        mean_out [b * 32 + d]      = mask ? 0.0f : (float)mean;
        scale_out[b * 32 + d]      = mask ? scl0 : scl;
        mean_out [b * 32 + 16 + d] = mask ? (float)mean : 0.0f;
        scale_out[b * 32 + 16 + d] = mask ? scl : scl0;
    }
}

// ---------------------------------------------------------------------------
// K2: per-point raw masked x_crd row, sq = sum(x_crd^2), and normalized
// channel sums Tc (crd half), Tf (ftr half).  16384 threads.
// ---------------------------------------------------------------------------
__global__ __launch_bounds__(256) void knn_prep(
    const float* __restrict__ x, const float* __restrict__ features,
    const float* __restrict__ mean_, const float* __restrict__ scale_,
    float* __restrict__ xcrd, float* __restrict__ sq,
    float* __restrict__ Tc, float* __restrict__ Tf)
{
    int t = blockIdx.x * 256 + threadIdx.x;      // (b,n) flat, 0..16383
    int b = t >> 11;
    float tc = 0.f, tf = 0.f, s = 0.f;
    float row[D];
#pragma unroll
    for (int d = 0; d < D; ++d) {
        float xv = x[(size_t)t * D + d];
        bool mask = features[b * D + d] > 0.1f;
        float xc = mask ? 0.f : xv;
        float xf = mask ? xv : 0.f;
        row[d] = xc;
        s += xc * xc;                            // sequential, mirrors ref sq
        float vc = (xc - mean_[b * 32 + d])      * scale_[b * 32 + d];
        vc = fminf(10.f, fmaxf(-10.f, vc));
        float vf = (xf - mean_[b * 32 + 16 + d]) * scale_[b * 32 + 16 + d];
        vf = fminf(10.f, fmaxf(-10.f, vf));
        tc += vc; tf += vf;
    }
#pragma unroll
    for (int d = 0; d < D; d += 4)
        *(float4*)(xcrd + (size_t)t * D + d) =
            make_float4(row[d], row[d+1], row[d+2], row[d+3]);
    sq[t] = s; Tc[t] = tc; Tf[t] = tf;
}

// ---------------------------------------------------------------------------
// K3: transpose W (DM,K)->(K,DM); bias const; pe_loss scalar.  1 block x 256.
// ---------------------------------------------------------------------------
__global__ __launch_bounds__(256) void knn_wprep(
    const float* __restrict__ Wc, const float* __restrict__ Wf,
    const float* __restrict__ pec, const float* __restrict__ pef,
    float* __restrict__ WcT, float* __restrict__ WfT,
    float* __restrict__ cbias, float* __restrict__ pe_loss_out)
{
    int dm = threadIdx.x;
    float cb = 0.f, al = 0.f;
#pragma unroll
    for (int p = 0; p < D; ++p)
        cb += pec[p * DM + dm] + pef[p * DM + dm];
#pragma unroll
    for (int p = 0; p < D; ++p)
        al += fabsf(pec[p * DM + dm]) + fabsf(pef[p * DM + dm]);
    cbias[dm] = cb;
#pragma unroll
    for (int k = 0; k < KNN; ++k) {
        WcT[k * DM + dm] = Wc[dm * KNN + k];
        WfT[k * DM + dm] = Wf[dm * KNN + k];
    }
    __shared__ float red[256];
    red[dm] = al; __syncthreads();
    for (int st = 128; st > 0; st >>= 1) {
        if (dm < st) red[dm] += red[dm + st];
        __syncthreads();
    }
    if (dm == 0) pe_loss_out[0] = red[0];
}

// ---------------------------------------------------------------------------
// K4: one wave (one 64-thread block) per query.
//  1) fill: 32 candidate keys/lane, key = (dist_bits<<11)|m  (lexicographic
//     (dist, index) — jax top_k tie semantics).  Distance arithmetic is
//     byte-identical to the round-1 kernel (ranks preserved).
//  2) in-register bitonic sort (ascending) of the lane's 32 keys — replaces
//     the per-round masked rescan (~6100 ops/query -> ~1300 once).
//  3) sorted list spilled to a lane-interleaved LDS region (each lane reads
//     only its own list -> no barrier ever needed).
//  4) 32 pop rounds: wave-min butterfly over 64 register heads; winner lane
//     advances via one ds_read_b64; all lanes accumulate the k-th matvec
//     column.
// ---------------------------------------------------------------------------
__global__ __launch_bounds__(64) void knn_main(
    const float* __restrict__ xcrd, const float* __restrict__ sq,
    const float* __restrict__ Tc, const float* __restrict__ Tf,
    const float* __restrict__ WcT, const float* __restrict__ WfT,
    const float* __restrict__ cbias, float* __restrict__ out)
{
    const int lane = threadIdx.x;                // 0..63
    const int qid  = blockIdx.x;                 // 0..16383
    const int b = qid >> 11;
    const int n = qid & 2047;

    const float* xb  = xcrd + (size_t)b * N * D;
    const float* sqb = sq + b * N;

    // query row
    float qx[D];
#pragma unroll
    for (int d = 0; d < D; d += 4) {
        float4 v = *(const float4*)(xb + (size_t)n * D + d);
        qx[d] = v.x; qx[d+1] = v.y; qx[d+2] = v.z; qx[d+3] = v.w;
    }
    const float sqn = sqb[n];

    // fill 32 candidate keys per lane (m = j*64 + lane)
    unsigned long long key[KNN];
#pragma unroll
    for (int j = 0; j < KNN; ++j) {
        int m = j * 64 + lane;
        const float* xm = xb + (size_t)m * D;
        float mr[D];
#pragma unroll
        for (int d = 0; d < D; d += 4) {
            float4 v = *(const float4*)(xm + d);
            mr[d] = v.x; mr[d+1] = v.y; mr[d+2] = v.z; mr[d+3] = v.w;
        }
        float dot = 0.f;
#pragma unroll
        for (int d = 0; d < D; ++d) dot += qx[d] * mr[d];  // sequential: self-dist == 0
        float d2 = sqn + sqb[m] - 2.0f * dot;
        float dist = sqrtf(fmaxf(d2, 0.f));
        key[j] = ((unsigned long long)__float_as_uint(dist) << 11) | (unsigned)m;
    }

    // in-register bitonic sort, ascending (static indices only)
#pragma unroll
    for (int kk = 2; kk <= KNN; kk <<= 1) {
#pragma unroll
        for (int jj = kk >> 1; jj > 0; jj >>= 1) {
#pragma unroll
            for (int i = 0; i < KNN; ++i) {
                int l = i ^ jj;
                if (l > i) {
                    bool asc = ((i & kk) == 0);
                    unsigned long long a = key[i], c = key[l];
                    bool sw = asc ? (a > c) : (a < c);
                    key[i] = sw ? c : a;
                    key[l] = sw ? a : c;
                }
            }
        }
    }

    // spill sorted entries 2..31 (lane-interleaved; own-lane reads only)
    __shared__ unsigned long long slist[KNN * 64];
#pragma unroll
    for (int j = 2; j < KNN; ++j)
        slist[j * 64 + lane] = key[j];

    unsigned long long head = key[0];
    unsigned long long nxt  = key[1];
    int ptr = 0;                                 // index of head in my list

    float acc[4] = {0.f, 0.f, 0.f, 0.f};
    const float* Tcb = Tc + b * N;
    const float* Tfb = Tf + b * N;
    const float Tcn = Tcb[n], Tfn = Tfb[n];

#pragma unroll 1
    for (int k = 0; k < KNN; ++k) {
        // wave-min butterfly over heads (u64 lexicographic (dist, m))
        unsigned long long g = head;
#pragma unroll
        for (int s = 32; s >= 1; s >>= 1) {
            unsigned long long o = __shfl_xor(g, s, 64);
            g = (o < g) ? o : g;
        }
        int wm = (int)(g & 2047u);               // k-th nearest index in batch

        bool win = (head == g);                  // keys are globally unique
        ptr += win ? 1 : 0;
        head = win ? nxt : head;
        int nidx = ptr + 1;
        unsigned long long cand =
            slist[(nidx < KNN ? nidx : KNN - 1) * 64 + lane];
        if (nidx >= KNN) cand = 0xFFFFFFFFFFFFFFFFull;
        nxt = win ? cand : nxt;

        float ak = Tcb[wm] - Tcn;
        float bk = Tfb[wm] - Tfn;
        const float* wc = WcT + k * DM + lane;
        const float* wf = WfT + k * DM + lane;
#pragma unroll
        for (int q = 0; q < 4; ++q)
            acc[q] += wc[q * 64] * ak + wf[q * 64] * bk;
    }

    size_t obase = (size_t)qid * DM + lane;
#pragma unroll
    for (int q = 0; q < 4; ++q)
        out[obase + q * 64] = acc[q] + cbias[lane + q * 64];
}

// ---------------------------------------------------------------------------
extern "C" void kernel_launch(void* const* d_in, const int* in_sizes, int n_in,
                              void* d_out, int out_size, void* d_ws, size_t ws_size,
                              hipStream_t stream)
{
    const float* x        = (const float*)d_in[0];   // (B,N,D)
    const float* features = (const float*)d_in[1];   // (B,D)
    const float* W_crd    = (const float*)d_in[2];   // (DM,K)
    const float* W_ftr    = (const float*)d_in[3];   // (DM,K)
    const float* pe_crd   = (const float*)d_in[4];   // (1,1,D,DM)
    const float* pe_ftr   = (const float*)d_in[5];   // (1,1,D,DM)
    // d_in[6] = k (constant 32), ignored

    float* out = (float*)d_out;                      // B*N*DM floats + 1 (pe_loss)

    float* base  = (float*)d_ws;
    float* xcrd  = base;                       // 262144
    float* sqv   = xcrd + (size_t)B * N * D;   // 16384
    float* Tc    = sqv  + B * N;               // 16384
    float* Tf    = Tc   + B * N;               // 16384
    float* mean_ = Tf   + B * N;               // 256
    float* scale = mean_ + B * 32;             // 256
    float* cbias = scale + B * 32;             // 256
    float* WcT   = cbias + DM;                 // 8192
    float* WfT   = WcT + KNN * DM;             // 8192

    knn_stats<<<B, 256, 0, stream>>>(x, features, mean_, scale);
    knn_prep <<<B * N / 256, 256, 0, stream>>>(x, features, mean_, scale,
                                               xcrd, sqv, Tc, Tf);
    knn_wprep<<<1, 256, 0, stream>>>(W_crd, W_ftr, pe_crd, pe_ftr,
                                     WcT, WfT, cbias, out + (size_t)out_size - 1);
    knn_main <<<B * N, 64, 0, stream>>>(xcrd, sqv, Tc, Tf,
                                        WcT, WfT, cbias, out);
}